// Round 13
// baseline (135.304 us; speedup 1.0000x reference)
//
#include <hip/hip_runtime.h>

typedef __attribute__((ext_vector_type(8))) short bf16x8;
typedef __attribute__((ext_vector_type(4))) float f32x4;
typedef __attribute__((ext_vector_type(2))) float pk2;

// Problem constants (from reference)
constexpr int B    = 8;
constexpr int N    = 4096;
constexpr int FIN  = 128;
constexpr int NT   = B * N;        // 32768
constexpr int H    = 4;
constexpr int C    = 64;
constexpr int D1   = H * C;        // 256
constexpr int E    = 524288;
constexpr int ETOT = E + NT;       // 557056
constexpr int NSLOT = 18;          // per-kt B slots: 0..16 = bh(nt0..16), 17 = blAtt(nt16)
constexpr int CAP  = 64;           // adjacency bucket capacity (max deg ~40, pad <= 63)

// bf16 round-to-nearest-even helpers
__device__ __forceinline__ unsigned short f2bf(float f) {
    unsigned u = __float_as_uint(f);
    return (unsigned short)((u + 0x7FFFu + ((u >> 16) & 1u)) >> 16);
}
__device__ __forceinline__ float bf2f(unsigned short b) {
    return __uint_as_float(((unsigned)b) << 16);
}

// ---- zero cnt + sentinels; XCD-pinned: graph g's counters zeroed on XCD g ----
__global__ __launch_bounds__(256) void k_zero(unsigned* __restrict__ cnt,
                                              float* __restrict__ asrc,
                                              unsigned short* __restrict__ xpb) {
    int g = blockIdx.x & 7, j = blockIdx.x >> 3;         // 128 blocks: 16/graph
    int i = (g << 12) + (j << 8) + threadIdx.x;
    cnt[i] = 0u;
    if (i < 4)  asrc[NT * H + i] = -1e30f;
    if (i < 64) reinterpret_cast<uint2*>(xpb)[(size_t)NT * 64 + i] = make_uint2(0u, 0u);
}

// ---- pack one layer's Bext = [W | Ws | Wd | 0] into per-kt slot layout ----
__device__ __forceinline__ void pack_body(
    const float* __restrict__ W, const float* __restrict__ as_,
    const float* __restrict__ ad_, unsigned short* __restrict__ pB, int g)
{
    int kt  = g / (NSLOT * 64);
    int rem = g % (NSLOT * 64);
    int slot = rem >> 6, l = rem & 63;
    int k0 = kt * 32 + 8 * (l >> 4);
    bool wantLo = (slot == 17);
    int nt = wantLo ? 16 : slot;
    int n  = nt * 16 + (l & 15);
    bf16x8 o;
    #pragma unroll
    for (int j = 0; j < 8; ++j) {
        int k = k0 + j;
        float v;
        if (n < 256) {
            v = W[k * D1 + n];
        } else if (n < 264) {
            int idx = n - 256, hh = idx & 3;
            const float* av = (idx < 4) ? as_ : ad_;
            float s = 0.f;
            #pragma unroll 8
            for (int c = 0; c < C; ++c) s += W[k * D1 + hh * C + c] * av[hh * C + c];
            v = s;
        } else {
            v = 0.f;
        }
        unsigned short hb = f2bf(v);
        o[j] = wantLo ? (short)f2bf(v - bf2f(hb)) : (short)hb;
    }
    *reinterpret_cast<bf16x8*>(pB + (size_t)g * 8) = o;
}

// ---- fused: pack (bid<54) | x0 + split + adjacency build, XCD-pinned.
//      Adjacency build: 4 INDEPENDENT atomic chains per thread (MLP x4). ----
__global__ __launch_bounds__(256) void k_combo(
    const float* __restrict__ x, const int* __restrict__ ei,
    unsigned short* __restrict__ hi, unsigned short* __restrict__ lo,
    float* __restrict__ out, unsigned* __restrict__ cnt, int* __restrict__ slots,
    const float* __restrict__ W1, const float* __restrict__ as1, const float* __restrict__ ad1,
    const float* __restrict__ W2, const float* __restrict__ as2, const float* __restrict__ ad2,
    unsigned short* __restrict__ pB1, unsigned short* __restrict__ pB2)
{
    int bid = blockIdx.x, t = threadIdx.x;

    if (bid < 54) {  // pack blocks (front of grid)
        if (bid < 18) pack_body(W1, as1, ad1, pB1, bid * 256 + t);
        else          pack_body(W2, as2, ad2, pB2, (bid - 18) * 256 + t);
        return;
    }

    int nb = bid - 54;                        // 0..4095
    int g  = nb & 7, loc = nb >> 3;           // graph g -> XCD g

    // part 1: x0 + split for 8 nodes of graph g
    {
        int node = (g << 12) + (loc << 3) + (t >> 5);
        int q = t & 31;
        float4 v = reinterpret_cast<const float4*>(x)[node * 32 + q];
        ushort4 h, l;
        h.x = f2bf(v.x); l.x = f2bf(v.x - bf2f(h.x));
        h.y = f2bf(v.y); l.y = f2bf(v.y - bf2f(h.y));
        h.z = f2bf(v.z); l.z = f2bf(v.z - bf2f(h.z));
        h.w = f2bf(v.w); l.w = f2bf(v.w - bf2f(h.w));
        reinterpret_cast<ushort4*>(hi)[node * 32 + q] = h;
        reinterpret_cast<ushort4*>(lo)[node * 32 + q] = l;
        float s = v.x + v.y + v.z + v.w;
        #pragma unroll
        for (int o = 16; o; o >>= 1) s += __shfl_xor(s, o);
        if (q == 0) {
            int n = node & (N - 1);
            out[g * (3 * N) + n] = s * (1.0f / 128.0f);
        }
    }

    // part 2: adjacency build for graph g's edges; 4 edges per thread,
    // independent atomic chains issued back-to-back for MLP.
    if (nb < 544) {
        int j = nb >> 3;                       // 0..67
        int eb = (j < 64) ? (g << 6) + j       // main edges: 64 blocks/graph
                          : 512 + (g << 2) + (j - 64);  // self-loops: 4 blocks/graph
        int e0 = eb * 1024 + t;
        int s0, d0, s1, d1, s2, d2, s3, d3;
        {
            int e = e0;
            if (e < E) { s0 = ei[e]; d0 = ei[E + e]; } else { s0 = d0 = e - E; }
            e = e0 + 256;
            if (e < E) { s1 = ei[e]; d1 = ei[E + e]; } else { s1 = d1 = e - E; }
            e = e0 + 512;
            if (e < E) { s2 = ei[e]; d2 = ei[E + e]; } else { s2 = d2 = e - E; }
            e = e0 + 768;
            if (e < E) { s3 = ei[e]; d3 = ei[E + e]; } else { s3 = d3 = e - E; }
        }
        unsigned p0 = atomicAdd(cnt + d0, 1u);
        unsigned p1 = atomicAdd(cnt + d1, 1u);
        unsigned p2 = atomicAdd(cnt + d2, 1u);
        unsigned p3 = atomicAdd(cnt + d3, 1u);
        slots[d0 * CAP + p0] = s0 * 4;
        slots[d1 * CAP + p1] = s1 * 4;
        slots[d2 * CAP + p2] = s2 * 4;
        slots[d3 * CAP + p3] = s3 * 4;
    }
}

// ---- MFMA GEMM: C[NT x 264] = A[NT x K] * Bext, software-pipelined, XCD-pinned.
//      BM=64; 4 waves = 2 wm x 2 wn; wave: 2 m-tiles x 9 slots. ----
template <int K, bool PAD>
__global__ __launch_bounds__(256) void k_mfma(
    const unsigned short* __restrict__ Ahi, const unsigned short* __restrict__ Alo,
    const unsigned short* __restrict__ pB,
    unsigned short* __restrict__ xpb, float* __restrict__ asrc, float* __restrict__ adst,
    const unsigned* __restrict__ cnt, int* __restrict__ slots)
{
    constexpr int KT = K / 32;
    int t = threadIdx.x, lane = t & 63, w = t >> 6;

    if (PAD && blockIdx.x >= NT / 64) {   // bucket padding blocks (XCD-pinned)
        int bl = blockIdx.x - NT / 64;    // 128 blocks: 16/graph
        int node = ((bl & 7) << 12) + ((bl >> 3) << 8) + t;
        int deg = (int)cnt[node];
        int dpad = ((deg + 1) & ~1) + 14;  // covers 3-pair lookahead overshoot
        int* sl = slots + (size_t)node * CAP;
        for (int i = deg; i < dpad; ++i) sl[i] = NT * 4;
        return;
    }

    int wm = w & 1, wn = w >> 1;
    // graph (bid&7) -> XCD (bid&7): rows of graph g computed on XCD g
    int m0 = ((blockIdx.x & 7) << 12) + ((blockIdx.x >> 3) << 6) + wm * 32;
    int sBase = wn * 9;

    f32x4 acc[2][9];
    #pragma unroll
    for (int i = 0; i < 2; ++i)
        #pragma unroll
        for (int j = 0; j < 9; ++j)
            acc[i][j] = (f32x4){0.f, 0.f, 0.f, 0.f};

    int aRow = m0 + (lane & 15);
    int aCol = 8 * (lane >> 4);
    const unsigned short* a0h = Ahi + (size_t)aRow * K + aCol;
    const unsigned short* a0l = Alo + (size_t)aRow * K + aCol;
    const unsigned short* bp  = pB + ((size_t)sBase * 64 + lane) * 8;

    bf16x8 bc[9], bn[9];
    bf16x8 ah0c, al0c, ah1c, al1c, ah0n, al0n, ah1n, al1n;

    #pragma unroll
    for (int j = 0; j < 9; ++j) bc[j] = *reinterpret_cast<const bf16x8*>(bp + j * 512);
    ah0c = *reinterpret_cast<const bf16x8*>(a0h);
    al0c = *reinterpret_cast<const bf16x8*>(a0l);
    ah1c = *reinterpret_cast<const bf16x8*>(a0h + 16 * K);
    al1c = *reinterpret_cast<const bf16x8*>(a0l + 16 * K);

    #pragma unroll
    for (int kt = 0; kt < KT; ++kt) {
        if (kt + 1 < KT) {
            const unsigned short* bpn = bp + (size_t)(kt + 1) * NSLOT * 64 * 8;
            #pragma unroll
            for (int j = 0; j < 9; ++j) bn[j] = *reinterpret_cast<const bf16x8*>(bpn + j * 512);
            ah0n = *reinterpret_cast<const bf16x8*>(a0h + (kt + 1) * 32);
            al0n = *reinterpret_cast<const bf16x8*>(a0l + (kt + 1) * 32);
            ah1n = *reinterpret_cast<const bf16x8*>(a0h + 16 * K + (kt + 1) * 32);
            al1n = *reinterpret_cast<const bf16x8*>(a0l + 16 * K + (kt + 1) * 32);
        }
        __builtin_amdgcn_sched_barrier(0);   // keep prefetch loads ahead of MFMAs
        if (wn == 0) {
            #pragma unroll
            for (int j = 0; j < 9; ++j) {
                acc[0][j] = __builtin_amdgcn_mfma_f32_16x16x32_bf16(ah0c, bc[j], acc[0][j], 0, 0, 0);
                acc[1][j] = __builtin_amdgcn_mfma_f32_16x16x32_bf16(ah1c, bc[j], acc[1][j], 0, 0, 0);
                acc[0][j] = __builtin_amdgcn_mfma_f32_16x16x32_bf16(al0c, bc[j], acc[0][j], 0, 0, 0);
                acc[1][j] = __builtin_amdgcn_mfma_f32_16x16x32_bf16(al1c, bc[j], acc[1][j], 0, 0, 0);
            }
        } else {
            #pragma unroll
            for (int j = 0; j < 8; ++j) {
                acc[0][j] = __builtin_amdgcn_mfma_f32_16x16x32_bf16(ah0c, bc[j], acc[0][j], 0, 0, 0);
                acc[1][j] = __builtin_amdgcn_mfma_f32_16x16x32_bf16(ah1c, bc[j], acc[1][j], 0, 0, 0);
                acc[0][j] = __builtin_amdgcn_mfma_f32_16x16x32_bf16(al0c, bc[j], acc[0][j], 0, 0, 0);
                acc[1][j] = __builtin_amdgcn_mfma_f32_16x16x32_bf16(al1c, bc[j], acc[1][j], 0, 0, 0);
            }
            acc[0][7] = __builtin_amdgcn_mfma_f32_16x16x32_bf16(ah0c, bc[8], acc[0][7], 0, 0, 0);
            acc[1][7] = __builtin_amdgcn_mfma_f32_16x16x32_bf16(ah1c, bc[8], acc[1][7], 0, 0, 0);
        }
        if (kt + 1 < KT) {
            #pragma unroll
            for (int j = 0; j < 9; ++j) bc[j] = bn[j];
            ah0c = ah0n; al0c = al0n; ah1c = ah1n; al1c = al1n;
        }
    }

    // epilogue: C layout col = lane&15, row = (lane>>4)*4 + r  [m89-verified]
    #pragma unroll
    for (int mt = 0; mt < 2; ++mt) {
        int rowB = m0 + mt * 16 + (lane >> 4) * 4;
        if (wn == 0) {
            #pragma unroll
            for (int j = 0; j < 9; ++j) {
                int col = j * 16 + (lane & 15);
                #pragma unroll
                for (int r = 0; r < 4; ++r)
                    xpb[(size_t)(rowB + r) * D1 + col] = f2bf(acc[mt][j][r]);
            }
        } else {
            #pragma unroll
            for (int j = 0; j < 8; ++j) {
                int nt = 9 + j;
                int col = nt * 16 + (lane & 15);
                #pragma unroll
                for (int r = 0; r < 4; ++r) {
                    int row = rowB + r;
                    float v = acc[mt][j][r];
                    if (col < 256)      xpb[(size_t)row * D1 + col] = f2bf(v);
                    else if (col < 260) asrc[row * H + (col - 256)] = v;
                    else if (col < 264) adst[row * H + (col - 260)] = v;
                }
            }
        }
    }
}

// ---- node aggregation: one wave per node; half-wave per edge (2 edges/step);
//      packed-f32 FMA + 3-slot circular prefetch (6 edges in flight) ----
__global__ __launch_bounds__(256) void k_node(
    const unsigned* __restrict__ cnt, const int* __restrict__ slots,
    const float* __restrict__ asrc, const float* __restrict__ adst,
    const unsigned short* __restrict__ xp,   // bf16 [NT+1][256]
    const float* __restrict__ bias, const float* __restrict__ pw,
    const float* __restrict__ pb,
    unsigned short* __restrict__ hhi, unsigned short* __restrict__ hlo,
    float* __restrict__ out, int sec)
{
    int bid = blockIdx.x;
    int w = threadIdx.x >> 6, lane = threadIdx.x & 63;
    int half = lane >> 5;                     // which edge of the pair
    int hl   = lane & 31;                     // lane within half: ch 8*hl..8*hl+7
    int head = hl >> 3;                       // 8 lanes per head
    // graph g = bid&7 pinned to XCD g; 4 nodes per block (one per wave)
    int node = ((bid & 7) << 12) | (((bid >> 3) << 2) + w);

    int deg = (int)cnt[node];                 // >= 1 (self loop)
    int dp  = (deg + 1) & ~1;                 // pair-rounded; overshoot hits sentinels
    const int* sl = slots + (size_t)node * CAP;
    float adh = adst[node * H + head];
    const uint4* xp4 = (const uint4*)xp;      // 8 bf16 per lane

    float den = 0.f;
    pk2 acc01 = {0.f, 0.f}, acc23 = {0.f, 0.f}, acc45 = {0.f, 0.f}, acc67 = {0.f, 0.f};

    #define PROC(aa, vv)                                                     \
    {                                                                        \
        float l  = aa + adh;                                                 \
        float ev = __expf(fmaxf(l, 0.2f * l));                               \
        den += ev;                                                           \
        pk2 e2 = {ev, ev};                                                   \
        pk2 t01 = {__uint_as_float(vv.x << 16), __uint_as_float(vv.x & 0xFFFF0000u)}; \
        pk2 t23 = {__uint_as_float(vv.y << 16), __uint_as_float(vv.y & 0xFFFF0000u)}; \
        pk2 t45 = {__uint_as_float(vv.z << 16), __uint_as_float(vv.z & 0xFFFF0000u)}; \
        pk2 t67 = {__uint_as_float(vv.w << 16), __uint_as_float(vv.w & 0xFFFF0000u)}; \
        acc01 = __builtin_elementwise_fma(e2, t01, acc01);                   \
        acc23 = __builtin_elementwise_fma(e2, t23, acc23);                   \
        acc45 = __builtin_elementwise_fma(e2, t45, acc45);                   \
        acc67 = __builtin_elementwise_fma(e2, t67, acc67);                   \
    }

    // 3-slot circular prefetch: pairs 0,2,4 preloaded; prefetch i+6 before use
    int   s_;
    float aX, aY, aZ, a_;
    uint4 vX, vY, vZ, v_;
    s_ = sl[0 + half]; aX = asrc[s_ + head]; vX = xp4[(s_ << 3) + hl];
    s_ = sl[2 + half]; aY = asrc[s_ + head]; vY = xp4[(s_ << 3) + hl];
    s_ = sl[4 + half]; aZ = asrc[s_ + head]; vZ = xp4[(s_ << 3) + hl];

    for (int i = 0; i < dp; i += 6) {
        s_ = sl[i + 6 + half];  a_ = asrc[s_ + head]; v_ = xp4[(s_ << 3) + hl];
        PROC(aX, vX); aX = a_; vX = v_;
        s_ = sl[i + 8 + half];  a_ = asrc[s_ + head]; v_ = xp4[(s_ << 3) + hl];
        PROC(aY, vY); aY = a_; vY = v_;
        s_ = sl[i + 10 + half]; a_ = asrc[s_ + head]; v_ = xp4[(s_ << 3) + hl];
        PROC(aZ, vZ); aZ = a_; vZ = v_;
    }
    #undef PROC

    // combine the two halves (lane l <-> l^32 hold same channels, different edges)
    den      += __shfl_xor(den, 32);
    acc01[0] += __shfl_xor(acc01[0], 32);
    acc01[1] += __shfl_xor(acc01[1], 32);
    acc23[0] += __shfl_xor(acc23[0], 32);
    acc23[1] += __shfl_xor(acc23[1], 32);
    acc45[0] += __shfl_xor(acc45[0], 32);
    acc45[1] += __shfl_xor(acc45[1], 32);
    acc67[0] += __shfl_xor(acc67[0], 32);
    acc67[1] += __shfl_xor(acc67[1], 32);

    float invd = 1.f / (den + 1e-16f);
    float4 b0 = reinterpret_cast<const float4*>(bias)[hl * 2];
    float4 b1 = reinterpret_cast<const float4*>(bias)[hl * 2 + 1];
    float4 p0 = reinterpret_cast<const float4*>(pw)[hl * 2];
    float4 p1 = reinterpret_cast<const float4*>(pw)[hl * 2 + 1];

    float h0 = fmaf(acc01[0], invd, b0.x), h1 = fmaf(acc01[1], invd, b0.y),
          h2 = fmaf(acc23[0], invd, b0.z), h3 = fmaf(acc23[1], invd, b0.w),
          h4 = fmaf(acc45[0], invd, b1.x), h5 = fmaf(acc45[1], invd, b1.y),
          h6 = fmaf(acc67[0], invd, b1.z), h7 = fmaf(acc67[1], invd, b1.w);
    h0 = h0 > 0.f ? h0 : __expf(h0) - 1.f;
    h1 = h1 > 0.f ? h1 : __expf(h1) - 1.f;
    h2 = h2 > 0.f ? h2 : __expf(h2) - 1.f;
    h3 = h3 > 0.f ? h3 : __expf(h3) - 1.f;
    h4 = h4 > 0.f ? h4 : __expf(h4) - 1.f;
    h5 = h5 > 0.f ? h5 : __expf(h5) - 1.f;
    h6 = h6 > 0.f ? h6 : __expf(h6) - 1.f;
    h7 = h7 > 0.f ? h7 : __expf(h7) - 1.f;

    if (hhi && half == 0) {
        unsigned short q0 = f2bf(h0), q1 = f2bf(h1), q2 = f2bf(h2), q3 = f2bf(h3),
                       q4 = f2bf(h4), q5 = f2bf(h5), q6 = f2bf(h6), q7 = f2bf(h7);
        uint4 hw, lw;
        hw.x = (unsigned)q0 | ((unsigned)q1 << 16);
        hw.y = (unsigned)q2 | ((unsigned)q3 << 16);
        hw.z = (unsigned)q4 | ((unsigned)q5 << 16);
        hw.w = (unsigned)q6 | ((unsigned)q7 << 16);
        lw.x = (unsigned)f2bf(h0 - bf2f(q0)) | ((unsigned)f2bf(h1 - bf2f(q1)) << 16);
        lw.y = (unsigned)f2bf(h2 - bf2f(q2)) | ((unsigned)f2bf(h3 - bf2f(q3)) << 16);
        lw.z = (unsigned)f2bf(h4 - bf2f(q4)) | ((unsigned)f2bf(h5 - bf2f(q5)) << 16);
        lw.w = (unsigned)f2bf(h6 - bf2f(q6)) | ((unsigned)f2bf(h7 - bf2f(q7)) << 16);
        reinterpret_cast<uint4*>(hhi)[node * 32 + hl] = hw;
        reinterpret_cast<uint4*>(hlo)[node * 32 + hl] = lw;
    }

    float p = h0 * p0.x + h1 * p0.y + h2 * p0.z + h3 * p0.w
            + h4 * p1.x + h5 * p1.y + h6 * p1.z + h7 * p1.w;
    #pragma unroll
    for (int o = 16; o; o >>= 1) p += __shfl_xor(p, o);
    if (lane == 0) {
        int b = node >> 12;
        int n = node & (N - 1);
        out[b * (3 * N) + sec * N + n] = p + pb[0];
    }
}

extern "C" void kernel_launch(void* const* d_in, const int* in_sizes, int n_in,
                              void* d_out, int out_size, void* d_ws, size_t ws_size,
                              hipStream_t stream) {
    const float* x   = (const float*)d_in[0];
    const int*   ei  = (const int*)d_in[1];
    const float* W1  = (const float*)d_in[2];
    const float* as1 = (const float*)d_in[3];
    const float* ad1 = (const float*)d_in[4];
    const float* b1  = (const float*)d_in[5];
    const float* W2  = (const float*)d_in[6];
    const float* as2 = (const float*)d_in[7];
    const float* ad2 = (const float*)d_in[8];
    const float* b2  = (const float*)d_in[9];
    const float* pw1 = (const float*)d_in[10];
    const float* pb1 = (const float*)d_in[11];
    const float* pw2 = (const float*)d_in[12];
    const float* pb2 = (const float*)d_in[13];
    float* out = (float*)d_out;

    // workspace layout (16B aligned blocks); xpb/asrc have +1 sentinel row
    unsigned short* xpb  = (unsigned short*)d_ws;             // (NT+1)*D1 bf16
    unsigned short* xhi  = xpb  + (size_t)(NT + 1) * D1;      // NT*FIN
    unsigned short* xlo  = xhi  + (size_t)NT * FIN;           // NT*FIN
    unsigned short* h1hi = xlo  + (size_t)NT * FIN;           // NT*D1
    unsigned short* h1lo = h1hi + (size_t)NT * D1;            // NT*D1
    float*    asrc   = (float*)(h1lo + (size_t)NT * D1);      // (NT+1)*H
    float*    adst   = asrc + (size_t)(NT + 1) * H;           // NT*H
    unsigned short* pB1 = (unsigned short*)(adst + (size_t)NT * H); // 4*18*64*8
    unsigned short* pB2 = pB1 + (size_t)4 * NSLOT * 64 * 8;         // 8*18*64*8
    unsigned* cnt    = (unsigned*)(pB2 + (size_t)8 * NSLOT * 64 * 8); // NT
    int*      slots  = (int*)(cnt + NT);                      // NT*CAP

    // 6 dispatches total
    k_zero<<<NT / 256, 256, 0, stream>>>(cnt, asrc, xpb);
    k_combo<<<54 + NT / 8, 256, 0, stream>>>(x, ei, xhi, xlo, out, cnt, slots,
                                             W1, as1, ad1, W2, as2, ad2, pB1, pB2);

    // ---------------- layer 1 (K = 128) ----------------
    k_mfma<128, true><<<NT / 64 + NT / 256, 256, 0, stream>>>(
        xhi, xlo, pB1, xpb, asrc, adst, cnt, slots);
    k_node<<<NT / 4, 256, 0, stream>>>(cnt, slots, asrc, adst, xpb,
                                       b1, pw1, pb1, h1hi, h1lo, out, 1);

    // ---------------- layer 2 (K = 256) ----------------
    k_mfma<256, false><<<NT / 64, 256, 0, stream>>>(
        h1hi, h1lo, pB2, xpb, asrc, adst, cnt, slots);
    k_node<<<NT / 4, 256, 0, stream>>>(cnt, slots, asrc, adst, xpb,
                                       b2, pw2, pb2, nullptr, nullptr, out, 2);
}